// Round 6
// baseline (424.737 us; speedup 1.0000x reference)
//
#include <hip/hip_runtime.h>
#include <math.h>

#define LEN 17821
#define DMODEL 384
#define NHEAD 8
#define DHEAD 48
#define WSZ (384 * 384)
#define NYT 279              // ceil(LEN/64)

typedef float floatx4 __attribute__((ext_vector_type(4)));
typedef short shortx8 __attribute__((ext_vector_type(8)));
typedef unsigned short ushort;

__device__ inline ushort f2bf(float f) {
    unsigned int u = __float_as_uint(f);
    u += 0x7FFFu + ((u >> 16) & 1u);
    return (ushort)(u >> 16);
}
__device__ inline float bf2f(ushort s) {
    return __uint_as_float(((unsigned int)s) << 16);
}

// ---------------------------------------------------------------------------
// Weight prep: 5 jobs, each emits a [384,384] bf16 matrix.
// ---------------------------------------------------------------------------
__global__ __launch_bounds__(256)
void prep_w(const float* __restrict__ Wval, const float* __restrict__ Woff,
            const float* __restrict__ Wattn, const float* __restrict__ Wout,
            const float* __restrict__ w1xy, const float* __restrict__ w1zd,
            const float* __restrict__ w2xy, const float* __restrict__ w2zd,
            ushort* __restrict__ wv, ushort* __restrict__ woa,
            ushort* __restrict__ wo, ushort* __restrict__ w1b,
            ushort* __restrict__ w2b) {
    int idx = blockIdx.x * 256 + threadIdx.x;
    if (idx >= WSZ) return;
    int n = idx / 384, k = idx - n * 384;
    int job = blockIdx.y;
    float v; ushort* dst;
    if (job == 0) { v = Wval[idx]; dst = wv; }
    else if (job == 1) {
        v = n < 256 ? Woff[n * 384 + k] : Wattn[(n - 256) * 384 + k];
        dst = woa;
    } else if (job == 2) { v = Wout[idx]; dst = wo; }
    else if (job == 3) {
        v = n < 256 ? (k < 256 ? w1xy[n * 256 + k] : 0.f)
                    : (k >= 256 ? w1zd[(n - 256) * 128 + (k - 256)] : 0.f);
        dst = w1b;
    } else {
        v = n < 256 ? (k < 256 ? w2xy[n * 256 + k] : 0.f)
                    : (k >= 256 ? w2zd[(n - 256) * 128 + (k - 256)] : 0.f);
        dst = w2b;
    }
    dst[idx] = f2bf(v);
}

__global__ __launch_bounds__(384)
void prep_b(const float* __restrict__ boff, const float* __restrict__ battn,
            const float* __restrict__ b1xy, const float* __restrict__ b1zd,
            const float* __restrict__ b2xy, const float* __restrict__ b2zd,
            const float* __restrict__ g1xy, const float* __restrict__ be1xy,
            const float* __restrict__ g1zd, const float* __restrict__ be1zd,
            const float* __restrict__ g2xy, const float* __restrict__ be2xy,
            const float* __restrict__ g2zd, const float* __restrict__ be2zd,
            float* __restrict__ boa, float* __restrict__ b1c,
            float* __restrict__ b2c, float* __restrict__ l1g,
            float* __restrict__ l1b, float* __restrict__ l2g,
            float* __restrict__ l2b) {
    int i = threadIdx.x;
    bool lo = i < 256; int j = lo ? i : i - 256;
    boa[i] = lo ? boff[i] : battn[j];
    b1c[i] = lo ? b1xy[i] : b1zd[j];
    b2c[i] = lo ? b2xy[i] : b2zd[j];
    l1g[i] = lo ? g1xy[i] : g1zd[j];
    l1b[i] = lo ? be1xy[i] : be1zd[j];
    l2g[i] = lo ? g2xy[i] : g2zd[j];
    l2b[i] = lo ? be2xy[i] : be2zd[j];
}

// ---------------------------------------------------------------------------
// src_bf = bf16(src); q_bf = bf16(src + pos).
// ---------------------------------------------------------------------------
__global__ __launch_bounds__(256)
void cvt_add(const float* __restrict__ src, const float* __restrict__ pos,
             ushort* __restrict__ src_bf, ushort* __restrict__ q_bf, int n8) {
    int i = blockIdx.x * 256 + threadIdx.x;
    if (i >= n8) return;
    float4 s0 = ((const float4*)src)[i * 2], s1 = ((const float4*)src)[i * 2 + 1];
    float4 p0 = ((const float4*)pos)[i * 2], p1 = ((const float4*)pos)[i * 2 + 1];
    shortx8 sb, qb;
    sb[0] = f2bf(s0.x); sb[1] = f2bf(s0.y); sb[2] = f2bf(s0.z); sb[3] = f2bf(s0.w);
    sb[4] = f2bf(s1.x); sb[5] = f2bf(s1.y); sb[6] = f2bf(s1.z); sb[7] = f2bf(s1.w);
    qb[0] = f2bf(s0.x + p0.x); qb[1] = f2bf(s0.y + p0.y);
    qb[2] = f2bf(s0.z + p0.z); qb[3] = f2bf(s0.w + p0.w);
    qb[4] = f2bf(s1.x + p1.x); qb[5] = f2bf(s1.y + p1.y);
    qb[6] = f2bf(s1.z + p1.z); qb[7] = f2bf(s1.w + p1.w);
    ((shortx8*)src_bf)[i] = sb;
    ((shortx8*)q_bf)[i] = qb;
}

// ---------------------------------------------------------------------------
// gemm64 v2: ONE WAVE per 64x64 tile, K=384, NO LDS. MFMA fragments are
// loaded directly from row-major global (quad-groups give 64B segments,
// L2-resident working set per XCD). Ping-pong register double-buffer.
// ---------------------------------------------------------------------------
template<bool RELU, bool HAS_RES, bool OUT_BF>
__device__ __forceinline__
void gemm64_core(int x, int y, const ushort* __restrict__ A,
                 const ushort* __restrict__ W, const float* __restrict__ bias,
                 const ushort* __restrict__ Res, float* __restrict__ Cf,
                 ushort* __restrict__ Cb) {
    int lane = threadIdx.x;
    int l15 = lane & 15, quad = lane >> 4;

    const ushort* ap[4];
    const ushort* wp[4];
    #pragma unroll
    for (int i = 0; i < 4; ++i) {
        // OOB A-rows (y=278 tail) read benign ws garbage; never stored.
        ap[i] = A + (size_t)(y * 64 + i * 16 + l15) * 384 + quad * 8;
        wp[i] = W + (size_t)(x * 64 + i * 16 + l15) * 384 + quad * 8;
    }

    floatx4 acc[4][4];
    #pragma unroll
    for (int i = 0; i < 4; ++i)
        #pragma unroll
        for (int j = 0; j < 4; ++j) acc[i][j] = (floatx4){0.f, 0.f, 0.f, 0.f};

    shortx8 a0[4], b0[4], a1[4], b1[4];
    #pragma unroll
    for (int i = 0; i < 4; ++i) {
        a0[i] = *(const shortx8*)(ap[i]);
        b0[i] = *(const shortx8*)(wp[i]);
    }

    #pragma unroll
    for (int kt = 0; kt < 12; kt += 2) {
        #pragma unroll
        for (int i = 0; i < 4; ++i) {
            a1[i] = *(const shortx8*)(ap[i] + (kt + 1) * 32);
            b1[i] = *(const shortx8*)(wp[i] + (kt + 1) * 32);
        }
        #pragma unroll
        for (int i = 0; i < 4; ++i)
            #pragma unroll
            for (int j = 0; j < 4; ++j)
                acc[i][j] = __builtin_amdgcn_mfma_f32_16x16x32_bf16(
                    a0[i], b0[j], acc[i][j], 0, 0, 0);
        if (kt + 2 < 12) {
            #pragma unroll
            for (int i = 0; i < 4; ++i) {
                a0[i] = *(const shortx8*)(ap[i] + (kt + 2) * 32);
                b0[i] = *(const shortx8*)(wp[i] + (kt + 2) * 32);
            }
        }
        #pragma unroll
        for (int i = 0; i < 4; ++i)
            #pragma unroll
            for (int j = 0; j < 4; ++j)
                acc[i][j] = __builtin_amdgcn_mfma_f32_16x16x32_bf16(
                    a1[i], b1[j], acc[i][j], 0, 0, 0);
    }

    #pragma unroll
    for (int j = 0; j < 4; ++j) {
        int col = x * 64 + j * 16 + l15;
        float bv = bias[col];
        #pragma unroll
        for (int i = 0; i < 4; ++i) {
            #pragma unroll
            for (int rr = 0; rr < 4; ++rr) {
                int row = y * 64 + i * 16 + quad * 4 + rr;
                if (row < LEN) {
                    float v = acc[i][j][rr] + bv;
                    if (RELU) v = fmaxf(v, 0.f);
                    if (HAS_RES) v += bf2f(Res[(size_t)row * 384 + col]);
                    if (OUT_BF) Cb[(size_t)row * 384 + col] = f2bf(v);
                    else        Cf[(size_t)row * 384 + col] = v;
                }
            }
        }
    }
}

// Generic N=384 GEMM: grid 8*35*6 = 1680 blocks of 64 threads.
// XCD swizzle: xcd = bid&7 owns y-range [xcd*35, xcd*35+35).
template<bool RELU, bool HAS_RES, bool OUT_BF>
__global__ __launch_bounds__(64)
void gemm64_k(const ushort* __restrict__ A, const ushort* __restrict__ W,
              const float* __restrict__ bias, const ushort* __restrict__ Res,
              float* __restrict__ Cf, ushort* __restrict__ Cb) {
    int bid = blockIdx.x;
    int xcd = bid & 7, l = bid >> 3;
    int y = xcd * 35 + l / 6;
    int x = l % 6;
    if (y >= NYT) return;
    gemm64_core<RELU, HAS_RES, OUT_BF>(x, y, A, W, bias, Res, Cf, Cb);
}

// Fused value+offattn GEMM: grid 8*35*12 = 3360; x<6 -> value (bf16),
// x>=6 -> offattn (fp32).
__global__ __launch_bounds__(64)
void vq64(const ushort* __restrict__ s0, const ushort* __restrict__ s1,
          const ushort* __restrict__ wv, const ushort* __restrict__ woa,
          const float* __restrict__ bval, const float* __restrict__ boa,
          ushort* __restrict__ vout, float* __restrict__ oaout) {
    int bid = blockIdx.x;
    int xcd = bid & 7, l = bid >> 3;
    int y = xcd * 35 + l / 12;
    int x = l % 12;
    if (y >= NYT) return;
    if (x < 6)
        gemm64_core<false, false, true>(x, y, s0, wv, bval, nullptr, nullptr, vout);
    else
        gemm64_core<false, false, false>(x - 6, y, s1, woa, boa, nullptr, oaout, nullptr);
}

// ---------------------------------------------------------------------------
// MSDA v4: per-corner (weight, row byte-offset) pairs in padded LDS;
// XCD swizzle on token chunks. (unchanged, verified round 4)
// ---------------------------------------------------------------------------
#define MTOK 8
__global__ __launch_bounds__(384)
void msda_v4(const ushort* __restrict__ value,   // [LEN,384] bf16
             const float* __restrict__ offattn,  // [LEN,384] fp32
             const float* __restrict__ refpts,   // [LEN,4,2]
             ushort* __restrict__ out) {         // [LEN,384] bf16
    __shared__ float saw[MTOK * 128];
    __shared__ int   sbuf[MTOK * 8 * 65 * 2];
    constexpr int Wi[4]  = {134, 67, 34, 17};
    constexpr int Hi[4]  = {100, 50, 25, 13};
    constexpr int STi[4] = {0, 13400, 16750, 17600};
    int b = blockIdx.x;                  // grid = 2232 = 8*279
    int nc = (b & 7) * 279 + (b >> 3);
    int t0 = nc * MTOK;
    if (t0 >= LEN) return;
    int tid = threadIdx.x;

    if (tid < MTOK * 8) {
        int ti = tid >> 3, h = tid & 7, t = t0 + ti;
        if (t < LEN) {
            const float* lg = offattn + (size_t)t * 384 + 256 + h * 16;
            float w[16], mx = -3.4e38f;
            #pragma unroll
            for (int s = 0; s < 16; ++s) { w[s] = lg[s]; mx = fmaxf(mx, w[s]); }
            float sum = 0.f;
            #pragma unroll
            for (int s = 0; s < 16; ++s) { w[s] = __expf(w[s] - mx); sum += w[s]; }
            float inv = 1.0f / sum;
            #pragma unroll
            for (int s = 0; s < 16; ++s) saw[ti * 128 + h * 16 + s] = w[s] * inv;
        }
    }
    __syncthreads();

    for (int idx = tid; idx < MTOK * 128; idx += 384) {
        int ti = idx >> 7, rem = idx & 127, h = rem >> 4, p = rem & 15;
        int lvl = p >> 2, pp = p & 3;
        int t = t0 + ti;
        if (t < LEN) {
            int Wl = Wi[lvl], Hl = Hi[lvl];
            const float* op = offattn + (size_t)t * 384 + h * 32 + lvl * 8 + pp * 2;
            float ox = op[0], oy = op[1];
            float rx = refpts[(size_t)t * 8 + lvl * 2];
            float ry = refpts[(size_t)t * 8 + lvl * 2 + 1];
            float x = rx * (float)Wl + ox - 0.5f;
            float y = ry * (float)Hl + oy - 0.5f;
            float x0f = floorf(x), y0f = floorf(y);
            float dx = x - x0f, dy = y - y0f;
            int x0 = (int)x0f, y0 = (int)y0f;
            float aw = saw[ti * 128 + h * 16 + p];
            float cw[4] = {(1.f - dx) * (1.f - dy), dx * (1.f - dy),
                           (1.f - dx) * dy, dx * dy};
            int base = ((ti * 8 + h) * 65 + p * 4) * 2;
            #pragma unroll
            for (int c2 = 0; c2 < 4; ++c2) {
                int xi = x0 + (c2 & 1), yi = y0 + (c2 >> 1);
                bool valid = (xi >= 0) & (xi < Wl) & (yi >= 0) & (yi < Hl);
                int xc = min(max(xi, 0), Wl - 1);
                int yc = min(max(yi, 0), Hl - 1);
                float s = valid ? aw * cw[c2] : 0.f;
                int off = (STi[lvl] + yc * Wl + xc) * 768;  // row byte offset
                sbuf[base + c2 * 2]     = __float_as_int(s);
                sbuf[base + c2 * 2 + 1] = off;
            }
        }
    }
    __syncthreads();

    int ti = tid / 48;
    int r = tid - ti * 48;
    int h = r / 6;
    int c = r - h * 6;
    int t = t0 + ti;
    if (t >= LEN) return;
    const char* vb = (const char*)value + (h * DHEAD + c * 8) * 2;
    float a[8] = {};
    int gb = (ti * 8 + h) * 65 * 2;
    #pragma unroll 8
    for (int pc = 0; pc < 64; ++pc) {
        int2 pr = *(int2*)&sbuf[gb + pc * 2];
        float s = __int_as_float(pr.x);
        shortx8 g = *(const shortx8*)(vb + pr.y);
        #pragma unroll
        for (int e = 0; e < 8; ++e) a[e] += s * bf2f(g[e]);
    }
    shortx8 o;
    #pragma unroll
    for (int e = 0; e < 8; ++e) o[e] = f2bf(a[e]);
    *(shortx8*)(out + (size_t)t * 384 + h * DHEAD + c * 8) = o;
}

// ---------------------------------------------------------------------------
// LN v2: one wave per token, lane l covers cols {l, l+64, ..., l+320}
// (4 xy + 2 zd per lane). Shuffle butterfly reduce; no LDS.
// ---------------------------------------------------------------------------
template<bool OUT_F32>
__global__ __launch_bounds__(256)
void ln_v2(const ushort* __restrict__ X, const float* __restrict__ g,
           const float* __restrict__ b, ushort* __restrict__ ob,
           float* __restrict__ of) {
    int w = threadIdx.x >> 6, lane = threadIdx.x & 63;
    int t = blockIdx.x * 4 + w;
    if (t >= LEN) return;
    float x[6];
    #pragma unroll
    for (int m = 0; m < 6; ++m)
        x[m] = bf2f(X[(size_t)t * 384 + lane + m * 64]);
    float sx = x[0] + x[1] + x[2] + x[3];
    float qx = x[0]*x[0] + x[1]*x[1] + x[2]*x[2] + x[3]*x[3];
    float sz = x[4] + x[5];
    float qz = x[4]*x[4] + x[5]*x[5];
    #pragma unroll
    for (int off = 32; off > 0; off >>= 1) {
        sx += __shfl_xor(sx, off);
        qx += __shfl_xor(qx, off);
        sz += __shfl_xor(sz, off);
        qz += __shfl_xor(qz, off);
    }
    float mx = sx * (1.f / 256.f), vx = qx * (1.f / 256.f) - mx * mx;
    float mz = sz * (1.f / 128.f), vz = qz * (1.f / 128.f) - mz * mz;
    float ivx = rsqrtf(vx + 1e-5f), ivz = rsqrtf(vz + 1e-5f);
    #pragma unroll
    for (int m = 0; m < 6; ++m) {
        int c = lane + m * 64;
        float mean = m < 4 ? mx : mz;
        float iv   = m < 4 ? ivx : ivz;
        float o = (x[m] - mean) * iv * g[c] + b[c];
        if (OUT_F32) of[(size_t)t * 384 + c] = o;
        else         ob[(size_t)t * 384 + c] = f2bf(o);
    }
}

// ---------------------------------------------------------------------------
extern "C" void kernel_launch(void* const* d_in, const int* in_sizes, int n_in,
                              void* d_out, int out_size, void* d_ws, size_t ws_size,
                              hipStream_t stream) {
    const float* src    = (const float*)d_in[0];
    const float* pos    = (const float*)d_in[3];
    const float* refpts = (const float*)d_in[4];
    const float* W_off  = (const float*)d_in[8];
    const float* b_off  = (const float*)d_in[9];
    const float* W_attn = (const float*)d_in[10];
    const float* b_attn = (const float*)d_in[11];
    const float* W_val  = (const float*)d_in[12];
    const float* b_val  = (const float*)d_in[13];
    const float* W_out  = (const float*)d_in[14];
    const float* b_out  = (const float*)d_in[15];
    const float* g1xy = (const float*)d_in[16]; const float* b1xy = (const float*)d_in[17];
    const float* g1zd = (const float*)d_in[18]; const float* b1zd = (const float*)d_in[19];
    const float* fxy_w1 = (const float*)d_in[20]; const float* fxy_b1 = (const float*)d_in[21];
    const float* fxy_w2 = (const float*)d_in[22]; const float* fxy_b2 = (const float*)d_in[23];
    const float* fxy_g  = (const float*)d_in[24]; const float* fxy_b  = (const float*)d_in[25];
    const float* fzd_w1 = (const float*)d_in[26]; const float* fzd_b1 = (const float*)d_in[27];
    const float* fzd_w2 = (const float*)d_in[28]; const float* fzd_b2 = (const float*)d_in[29];
    const float* fzd_g  = (const float*)d_in[30]; const float* fzd_b  = (const float*)d_in[31];

    float* out = (float*)d_out;
    size_t Rn = (size_t)LEN * DMODEL;

    float* f0 = (float*)d_ws;                 // offattn fp32
    ushort* sb = (ushort*)(f0 + Rn);
    ushort* s0 = sb;                          // src_bf, later ffn-hidden
    ushort* s1 = sb + Rn;                     // q_bf, later x1 (pre-LN1)
    ushort* s2 = sb + 2 * Rn;                 // value_bf, later x2 (pre-LN2)
    ushort* s3 = sb + 3 * Rn;                 // msda_bf, later h1 (post-LN1)
    ushort* wv  = sb + 4 * Rn;
    ushort* woa = wv + WSZ;
    ushort* wo  = woa + WSZ;
    ushort* w1b = wo + WSZ;
    ushort* w2b = w1b + WSZ;
    float* bp = (float*)(w2b + WSZ);
    float* boa = bp;        float* b1c = bp + 384;  float* b2c = bp + 768;
    float* l1g = bp + 1152; float* l1b = bp + 1536;
    float* l2g = bp + 1920; float* l2b = bp + 2304;

    prep_w<<<dim3((WSZ + 255) / 256, 5), 256, 0, stream>>>(
        W_val, W_off, W_attn, W_out, fxy_w1, fzd_w1, fxy_w2, fzd_w2,
        wv, woa, wo, w1b, w2b);
    prep_b<<<1, 384, 0, stream>>>(b_off, b_attn, fxy_b1, fzd_b1, fxy_b2, fzd_b2,
                                  g1xy, b1xy, g1zd, b1zd, fxy_g, fxy_b, fzd_g, fzd_b,
                                  boa, b1c, b2c, l1g, l1b, l2g, l2b);

    int n8 = (int)(Rn / 8);
    cvt_add<<<(n8 + 255) / 256, 256, 0, stream>>>(src, pos, s0, s1, n8);

    // value (bf16 -> s2) + offattn (fp32 -> f0), one dispatch
    vq64<<<8 * 35 * 12, 64, 0, stream>>>(s0, s1, wv, woa, b_val, boa, s2, f0);

    // MSDA -> s3 (bf16)
    msda_v4<<<8 * 279, 384, 0, stream>>>(s2, f0, refpts, s3);

    // x1 = msda @ Wo^T + bo + src  (bf16 -> s1)
    gemm64_k<false, true, true><<<8 * 35 * 6, 64, 0, stream>>>(
        s3, wo, b_out, s0, nullptr, s1);

    // h1 = LN1(x1) (bf16 -> s3)
    ln_v2<false><<<(LEN + 3) / 4, 256, 0, stream>>>(s1, l1g, l1b, s3, nullptr);

    // hidden = relu(h1 @ W1^T + b1) (bf16 -> s0)
    gemm64_k<true, false, true><<<8 * 35 * 6, 64, 0, stream>>>(
        s3, w1b, b1c, nullptr, nullptr, s0);

    // x2 = hidden @ W2^T + b2 + h1 (bf16 -> s2)
    gemm64_k<false, true, true><<<8 * 35 * 6, 64, 0, stream>>>(
        s0, w2b, b2c, s3, nullptr, s2);

    // out = LN2(x2) (fp32 -> d_out)
    ln_v2<true><<<(LEN + 3) / 4, 256, 0, stream>>>(s2, l2g, l2b, nullptr, out);
}

// Round 7
// 339.469 us; speedup vs baseline: 1.2512x; 1.2512x over previous
//
#include <hip/hip_runtime.h>
#include <math.h>

#define LEN 17821
#define DMODEL 384
#define NHEAD 8
#define DHEAD 48
#define WSZ (384 * 384)

typedef float floatx4 __attribute__((ext_vector_type(4)));
typedef short shortx8 __attribute__((ext_vector_type(8)));
typedef unsigned short ushort;

__device__ inline ushort f2bf(float f) {
    unsigned int u = __float_as_uint(f);
    u += 0x7FFFu + ((u >> 16) & 1u);
    return (ushort)(u >> 16);
}
__device__ inline float bf2f(ushort s) {
    return __uint_as_float(((unsigned int)s) << 16);
}

// ---------------------------------------------------------------------------
// Weight prep: 5 jobs, each emits a [384,384] bf16 matrix.
// ---------------------------------------------------------------------------
__global__ __launch_bounds__(256)
void prep_w(const float* __restrict__ Wval, const float* __restrict__ Woff,
            const float* __restrict__ Wattn, const float* __restrict__ Wout,
            const float* __restrict__ w1xy, const float* __restrict__ w1zd,
            const float* __restrict__ w2xy, const float* __restrict__ w2zd,
            ushort* __restrict__ wv, ushort* __restrict__ woa,
            ushort* __restrict__ wo, ushort* __restrict__ w1b,
            ushort* __restrict__ w2b) {
    int idx = blockIdx.x * 256 + threadIdx.x;
    if (idx >= WSZ) return;
    int n = idx / 384, k = idx - n * 384;
    int job = blockIdx.y;
    float v; ushort* dst;
    if (job == 0) { v = Wval[idx]; dst = wv; }
    else if (job == 1) {
        v = n < 256 ? Woff[n * 384 + k] : Wattn[(n - 256) * 384 + k];
        dst = woa;
    } else if (job == 2) { v = Wout[idx]; dst = wo; }
    else if (job == 3) {
        v = n < 256 ? (k < 256 ? w1xy[n * 256 + k] : 0.f)
                    : (k >= 256 ? w1zd[(n - 256) * 128 + (k - 256)] : 0.f);
        dst = w1b;
    } else {
        v = n < 256 ? (k < 256 ? w2xy[n * 256 + k] : 0.f)
                    : (k >= 256 ? w2zd[(n - 256) * 128 + (k - 256)] : 0.f);
        dst = w2b;
    }
    dst[idx] = f2bf(v);
}

__global__ __launch_bounds__(384)
void prep_b(const float* __restrict__ boff, const float* __restrict__ battn,
            const float* __restrict__ b1xy, const float* __restrict__ b1zd,
            const float* __restrict__ b2xy, const float* __restrict__ b2zd,
            const float* __restrict__ g1xy, const float* __restrict__ be1xy,
            const float* __restrict__ g1zd, const float* __restrict__ be1zd,
            const float* __restrict__ g2xy, const float* __restrict__ be2xy,
            const float* __restrict__ g2zd, const float* __restrict__ be2zd,
            float* __restrict__ boa, float* __restrict__ b1c,
            float* __restrict__ b2c, float* __restrict__ l1g,
            float* __restrict__ l1b, float* __restrict__ l2g,
            float* __restrict__ l2b) {
    int i = threadIdx.x;
    bool lo = i < 256; int j = lo ? i : i - 256;
    boa[i] = lo ? boff[i] : battn[j];
    b1c[i] = lo ? b1xy[i] : b1zd[j];
    b2c[i] = lo ? b2xy[i] : b2zd[j];
    l1g[i] = lo ? g1xy[i] : g1zd[j];
    l1b[i] = lo ? be1xy[i] : be1zd[j];
    l2g[i] = lo ? g2xy[i] : g2zd[j];
    l2b[i] = lo ? be2xy[i] : be2zd[j];
}

// ---------------------------------------------------------------------------
// src_bf = bf16(src); q_bf = bf16(src + pos).
// ---------------------------------------------------------------------------
__global__ __launch_bounds__(256)
void cvt_add(const float* __restrict__ src, const float* __restrict__ pos,
             ushort* __restrict__ src_bf, ushort* __restrict__ q_bf, int n8) {
    int i = blockIdx.x * 256 + threadIdx.x;
    if (i >= n8) return;
    float4 s0 = ((const float4*)src)[i * 2], s1 = ((const float4*)src)[i * 2 + 1];
    float4 p0 = ((const float4*)pos)[i * 2], p1 = ((const float4*)pos)[i * 2 + 1];
    shortx8 sb, qb;
    sb[0] = f2bf(s0.x); sb[1] = f2bf(s0.y); sb[2] = f2bf(s0.z); sb[3] = f2bf(s0.w);
    sb[4] = f2bf(s1.x); sb[5] = f2bf(s1.y); sb[6] = f2bf(s1.z); sb[7] = f2bf(s1.w);
    qb[0] = f2bf(s0.x + p0.x); qb[1] = f2bf(s0.y + p0.y);
    qb[2] = f2bf(s0.z + p0.z); qb[3] = f2bf(s0.w + p0.w);
    qb[4] = f2bf(s1.x + p1.x); qb[5] = f2bf(s1.y + p1.y);
    qb[6] = f2bf(s1.z + p1.z); qb[7] = f2bf(s1.w + p1.w);
    ((shortx8*)src_bf)[i] = sb;
    ((shortx8*)q_bf)[i] = qb;
}

// ---------------------------------------------------------------------------
// Merged value + offattn GEMM, register-prefetch K-loop. grid (6,140):
// bx<3 -> value (bf16 out), bx>=3 -> offattn (fp32 out). 128x128 tile, BK=32.
// ---------------------------------------------------------------------------
#define TSV 128
#define LSTRIDE 40

__global__ __launch_bounds__(256)
void vq_gemm(const ushort* __restrict__ sbq, const ushort* __restrict__ qbq,
             const ushort* __restrict__ wv, const ushort* __restrict__ woa,
             const float* __restrict__ bval, const float* __restrict__ boa,
             ushort* __restrict__ vout, float* __restrict__ oaout) {
    __shared__ ushort As[TSV * LSTRIDE];
    __shared__ ushort Ws[TSV * LSTRIDE];
    bool job = blockIdx.x >= 3;
    int bx = job ? blockIdx.x - 3 : blockIdx.x;
    const ushort* A = job ? qbq : sbq;
    const ushort* W = job ? woa : wv;
    const float* bias = job ? boa : bval;
    int tid = threadIdx.x;
    int lane = tid & 63, wave = tid >> 6;
    int wr = (wave >> 1) * 64, wc = (wave & 1) * 64;
    int l15 = lane & 15, quad = lane >> 4;
    int srow = tid >> 1, shalf = tid & 1;
    int by = blockIdx.y;
    int garow = by * TSV + srow;
    bool avalid = garow < LEN;
    const ushort* ap = A + (size_t)(avalid ? garow : 0) * 384 + shalf * 16;
    const ushort* wp = W + (size_t)(bx * TSV + srow) * 384 + shalf * 16;
    ushort* as_dst = &As[srow * LSTRIDE + shalf * 16];
    ushort* ws_dst = &Ws[srow * LSTRIDE + shalf * 16];

    floatx4 acc[4][4];
    #pragma unroll
    for (int i = 0; i < 4; ++i)
        #pragma unroll
        for (int j = 0; j < 4; ++j)
            acc[i][j] = (floatx4){0.f, 0.f, 0.f, 0.f};

    shortx8 a0 = *(const shortx8*)(ap);
    shortx8 a1 = *(const shortx8*)(ap + 8);
    shortx8 w0 = *(const shortx8*)(wp);
    shortx8 w1 = *(const shortx8*)(wp + 8);

    for (int k0 = 0; k0 < 384; k0 += 32) {
        __syncthreads();
        *(shortx8*)(as_dst + 0) = a0;
        *(shortx8*)(as_dst + 8) = a1;
        *(shortx8*)(ws_dst + 0) = w0;
        *(shortx8*)(ws_dst + 8) = w1;
        __syncthreads();
        if (k0 + 32 < 384) {            // prefetch next tile during compute
            a0 = *(const shortx8*)(ap + k0 + 32);
            a1 = *(const shortx8*)(ap + k0 + 40);
            w0 = *(const shortx8*)(wp + k0 + 32);
            w1 = *(const shortx8*)(wp + k0 + 40);
        }
        shortx8 af[4], bfr[4];
        #pragma unroll
        for (int i = 0; i < 4; ++i)
            af[i] = *(shortx8*)&As[(wr + i * 16 + l15) * LSTRIDE + quad * 8];
        #pragma unroll
        for (int j = 0; j < 4; ++j)
            bfr[j] = *(shortx8*)&Ws[(wc + j * 16 + l15) * LSTRIDE + quad * 8];
        #pragma unroll
        for (int i = 0; i < 4; ++i)
            #pragma unroll
            for (int j = 0; j < 4; ++j)
                acc[i][j] = __builtin_amdgcn_mfma_f32_16x16x32_bf16(
                    af[i], bfr[j], acc[i][j], 0, 0, 0);
    }

    #pragma unroll
    for (int j = 0; j < 4; ++j) {
        int col = bx * TSV + wc + j * 16 + l15;
        float bv = bias[col];
        #pragma unroll
        for (int i = 0; i < 4; ++i) {
            #pragma unroll
            for (int r = 0; r < 4; ++r) {
                int row = by * TSV + wr + i * 16 + quad * 4 + r;
                if (row < LEN) {
                    float v = acc[i][j][r] + bv;
                    if (job) oaout[(size_t)row * 384 + col] = v;
                    else     vout[(size_t)row * 384 + col] = f2bf(v);
                }
            }
        }
    }
}

// ---------------------------------------------------------------------------
// MSDA v3 (round-3 verified, 65 us): bf16 value gather, block = 8 tokens x
// 48 threads; softmax + coords in LDS; no XCD swizzle, no corner table.
// ---------------------------------------------------------------------------
#define MTOK 8
__global__ __launch_bounds__(384)
void msda_v3(const ushort* __restrict__ value,   // [LEN,384] bf16
             const float* __restrict__ offattn,  // [LEN,384] fp32
             const float* __restrict__ refpts,   // [LEN,4,2]
             ushort* __restrict__ out) {         // [LEN,384] bf16
    __shared__ int   sx0[MTOK * 128], sy0[MTOK * 128];
    __shared__ float sdx[MTOK * 128], sdy[MTOK * 128], saw[MTOK * 128];
    constexpr int Wi[4]  = {134, 67, 34, 17};
    constexpr int Hi[4]  = {100, 50, 25, 13};
    constexpr int STi[4] = {0, 13400, 16750, 17600};
    int t0 = blockIdx.x * MTOK;
    int tid = threadIdx.x;

    if (tid < MTOK * 8) {
        int ti = tid >> 3, h = tid & 7, t = t0 + ti;
        if (t < LEN) {
            const float* lg = offattn + (size_t)t * 384 + 256 + h * 16;
            float w[16], mx = -3.4e38f;
            #pragma unroll
            for (int s = 0; s < 16; ++s) { w[s] = lg[s]; mx = fmaxf(mx, w[s]); }
            float sum = 0.f;
            #pragma unroll
            for (int s = 0; s < 16; ++s) { w[s] = __expf(w[s] - mx); sum += w[s]; }
            float inv = 1.0f / sum;
            #pragma unroll
            for (int s = 0; s < 16; ++s) saw[ti * 128 + h * 16 + s] = w[s] * inv;
        }
    }
    for (int idx = tid; idx < MTOK * 128; idx += 384) {
        int ti = idx >> 7, rem = idx & 127, h = rem >> 4, p = rem & 15;
        int lvl = p >> 2, pp = p & 3;
        int t = t0 + ti;
        if (t < LEN) {
            float Wl = (float)Wi[lvl], Hl = (float)Hi[lvl];
            const float* op = offattn + (size_t)t * 384 + h * 32 + lvl * 8 + pp * 2;
            float ox = op[0], oy = op[1];
            float rx = refpts[(size_t)t * 8 + lvl * 2];
            float ry = refpts[(size_t)t * 8 + lvl * 2 + 1];
            float x = rx * Wl + ox - 0.5f;
            float y = ry * Hl + oy - 0.5f;
            float x0 = floorf(x), y0 = floorf(y);
            sx0[idx] = (int)x0; sy0[idx] = (int)y0;
            sdx[idx] = x - x0;  sdy[idx] = y - y0;
        }
    }
    __syncthreads();

    int ti = tid / 48;
    int r = tid - ti * 48;
    int h = r / 6;
    int c = r - h * 6;
    int t = t0 + ti;
    if (t >= LEN) return;
    const ushort* vb = value + h * DHEAD + c * 8;
    float a[8] = {};
    #pragma unroll
    for (int p = 0; p < 16; ++p) {
        const int lvl = p >> 2;
        const int Wl = Wi[lvl], Hl = Hi[lvl], st = STi[lvl];
        int base = ti * 128 + h * 16 + p;
        int x0 = sx0[base], y0 = sy0[base];
        float dx = sdx[base], dy = sdy[base], aw = saw[base];
        float cwv[4] = {(1.f - dx) * (1.f - dy), dx * (1.f - dy),
                        (1.f - dx) * dy, dx * dy};
        #pragma unroll
        for (int c2 = 0; c2 < 4; ++c2) {
            int xi = x0 + (c2 & 1), yi = y0 + (c2 >> 1);
            bool valid = (xi >= 0) & (xi < Wl) & (yi >= 0) & (yi < Hl);
            int xc = min(max(xi, 0), Wl - 1);
            int yc = min(max(yi, 0), Hl - 1);
            float s = valid ? aw * cwv[c2] : 0.f;
            shortx8 g = *(const shortx8*)(vb + (size_t)(st + yc * Wl + xc) * 384);
            #pragma unroll
            for (int k = 0; k < 8; ++k) a[k] += s * bf2f(g[k]);
        }
    }
    shortx8 o;
    #pragma unroll
    for (int k = 0; k < 8; ++k) o[k] = f2bf(a[k]);
    *(shortx8*)(out + (size_t)t * 384 + h * DHEAD + c * 8) = o;
}

// ---------------------------------------------------------------------------
// MEGA: out-proj + LN1 + FFN1(relu) + FFN2 + LN2, block = 32 rows x N=384.
// W staging now register-prefetched (load k+1 in flight during compute k).
// ---------------------------------------------------------------------------
#define MT 32
#define CST 392
#define WST 40

__global__ __launch_bounds__(256)
void mega_kernel(const ushort* __restrict__ Amsda, const float* __restrict__ src,
                 const ushort* __restrict__ Wo, const ushort* __restrict__ W1,
                 const ushort* __restrict__ W2,
                 const float* __restrict__ bo, const float* __restrict__ b1c,
                 const float* __restrict__ b2c,
                 const float* __restrict__ l1g, const float* __restrict__ l1b,
                 const float* __restrict__ l2g, const float* __restrict__ l2b,
                 float* __restrict__ h1f, float* __restrict__ outp) {
    __shared__ __align__(16) ushort Wbuf[384 * WST];   // 30720 B
    __shared__ __align__(16) ushort Cbuf[MT * CST];    // 25088 B
    ushort* Abuf = Cbuf;
    floatx4* pst4 = (floatx4*)Wbuf;
    floatx4* lnf  = (floatx4*)((char*)Wbuf + 4096);

    int tid = threadIdx.x;
    int lane = tid & 63, wave = tid >> 6;
    int wcol = wave * 96;
    int l15 = lane & 15, quad = lane >> 4;
    int by0 = blockIdx.x * MT;

    floatx4 acc[2][6];
    shortx8 wreg[6], areg;

    // ---------------- stage 1: src2 = msda @ Wo^T ----------------
    #pragma unroll
    for (int i = 0; i < 2; ++i)
        #pragma unroll
        for (int j = 0; j < 6; ++j) acc[i][j] = (floatx4){0.f, 0.f, 0.f, 0.f};

    if (tid < 128) {
        int gr = min(by0 + (tid >> 2), LEN - 1);
        areg = *(const shortx8*)(Amsda + (size_t)gr * 384 + (tid & 3) * 8);
    }
    #pragma unroll
    for (int cix = 0; cix < 6; ++cix) {
        int idx = cix * 256 + tid;
        wreg[cix] = *(const shortx8*)(Wo + (size_t)(idx >> 2) * 384 + (idx & 3) * 8);
    }

    for (int k0 = 0; k0 < 384; k0 += 32) {
        __syncthreads();
        if (tid < 128) *(shortx8*)(Abuf + (tid >> 2) * WST + (tid & 3) * 8) = areg;
        #pragma unroll
        for (int cix = 0; cix < 6; ++cix) {
            int idx = cix * 256 + tid;
            *(shortx8*)(Wbuf + (idx >> 2) * WST + (idx & 3) * 8) = wreg[cix];
        }
        __syncthreads();
        if (k0 + 32 < 384) {
            if (tid < 128) {
                int gr = min(by0 + (tid >> 2), LEN - 1);
                areg = *(const shortx8*)(Amsda + (size_t)gr * 384 + k0 + 32 + (tid & 3) * 8);
            }
            #pragma unroll
            for (int cix = 0; cix < 6; ++cix) {
                int idx = cix * 256 + tid;
                wreg[cix] = *(const shortx8*)(Wo + (size_t)(idx >> 2) * 384 + k0 + 32 + (idx & 3) * 8);
            }
        }
        shortx8 af[2];
        af[0] = *(shortx8*)(Abuf + (l15) * WST + quad * 8);
        af[1] = *(shortx8*)(Abuf + (16 + l15) * WST + quad * 8);
        #pragma unroll
        for (int j = 0; j < 6; ++j) {
            shortx8 bfr = *(shortx8*)(Wbuf + (wcol + j * 16 + l15) * WST + quad * 8);
            acc[0][j] = __builtin_amdgcn_mfma_f32_16x16x32_bf16(af[0], bfr, acc[0][j], 0, 0, 0);
            acc[1][j] = __builtin_amdgcn_mfma_f32_16x16x32_bf16(af[1], bfr, acc[1][j], 0, 0, 0);
        }
    }
    __syncthreads();

    // epilogue 1: x = src2 + b_out + src -> Cbuf (bf16)
    #pragma unroll
    for (int j = 0; j < 6; ++j) {
        int col = wcol + j * 16 + l15;
        float bv = bo[col];
        #pragma unroll
        for (int i = 0; i < 2; ++i)
            #pragma unroll
            for (int rr = 0; rr < 4; ++rr) {
                int row = i * 16 + quad * 4 + rr;
                int gr = min(by0 + row, LEN - 1);
                float x = acc[i][j][rr] + bv + src[(size_t)gr * 384 + col];
                Cbuf[row * CST + col] = f2bf(x);
            }
    }
    __syncthreads();

    // ---- LN1 ----
    {
        int row = tid >> 3, part = tid & 7;
        float sx = 0.f, qx = 0.f, sz = 0.f, qz = 0.f;
        #pragma unroll
        for (int m = 0; m < 6; ++m) {
            int c0 = part * 48 + m * 8;
            shortx8 v = *(shortx8*)(Cbuf + row * CST + c0);
            float cs = 0.f, cq = 0.f;
            #pragma unroll
            for (int e = 0; e < 8; ++e) { float x = bf2f(v[e]); cs += x; cq += x * x; }
            if (c0 < 256) { sx += cs; qx += cq; } else { sz += cs; qz += cq; }
        }
        pst4[row * 8 + part] = (floatx4){sx, qx, sz, qz};
    }
    __syncthreads();
    if (tid < MT) {
        floatx4 s = (floatx4){0.f, 0.f, 0.f, 0.f};
        #pragma unroll
        for (int p = 0; p < 8; ++p) s += pst4[tid * 8 + p];
        float mx = s[0] / 256.f, vx = s[1] / 256.f - mx * mx;
        float mz = s[2] / 128.f, vz = s[3] / 128.f - mz * mz;
        lnf[tid] = (floatx4){mx, rsqrtf(vx + 1e-5f), mz, rsqrtf(vz + 1e-5f)};
    }
    __syncthreads();
    {
        int row = tid >> 3, part = tid & 7;
        int gr = by0 + row;
        floatx4 L = lnf[row];
        #pragma unroll
        for (int m = 0; m < 6; ++m) {
            int c0 = part * 48 + m * 8;
            bool isxy = c0 < 256;
            float mean = isxy ? L[0] : L[2];
            float inv  = isxy ? L[1] : L[3];
            shortx8 v = *(shortx8*)(Cbuf + row * CST + c0);
            float4 g0 = *(const float4*)(l1g + c0), g1 = *(const float4*)(l1g + c0 + 4);
            float4 e0 = *(const float4*)(l1b + c0), e1 = *(const float4*)(l1b + c0 + 4);
            float gg[8] = {g0.x, g0.y, g0.z, g0.w, g1.x, g1.y, g1.z, g1.w};
            float ee[8] = {e0.x, e0.y, e0.z, e0.w, e1.x, e1.y, e1.z, e1.w};
            float h[8];
            shortx8 hb;
            #pragma unroll
            for (int e = 0; e < 8; ++e) {
                h[e] = (bf2f(v[e]) - mean) * inv * gg[e] + ee[e];
                hb[e] = f2bf(h[e]);
            }
            *(shortx8*)(Cbuf + row * CST + c0) = hb;
            if (gr < LEN) {
                *(float4*)(h1f + (size_t)gr * 384 + c0)     = make_float4(h[0], h[1], h[2], h[3]);
                *(float4*)(h1f + (size_t)gr * 384 + c0 + 4) = make_float4(h[4], h[5], h[6], h[7]);
            }
        }
    }
    __syncthreads();

    // ---------------- stage 2: hidden = relu(h1 @ W1^T + b1) ----------------
    #pragma unroll
    for (int i = 0; i < 2; ++i)
        #pragma unroll
        for (int j = 0; j < 6; ++j) acc[i][j] = (floatx4){0.f, 0.f, 0.f, 0.f};
    #pragma unroll
    for (int cix = 0; cix < 6; ++cix) {
        int idx = cix * 256 + tid;
        wreg[cix] = *(const shortx8*)(W1 + (size_t)(idx >> 2) * 384 + (idx & 3) * 8);
    }
    for (int k0 = 0; k0 < 384; k0 += 32) {
        __syncthreads();
        #pragma unroll
        for (int cix = 0; cix < 6; ++cix) {
            int idx = cix * 256 + tid;
            *(shortx8*)(Wbuf + (idx >> 2) * WST + (idx & 3) * 8) = wreg[cix];
        }
        __syncthreads();
        if (k0 + 32 < 384) {
            #pragma unroll
            for (int cix = 0; cix < 6; ++cix) {
                int idx = cix * 256 + tid;
                wreg[cix] = *(const shortx8*)(W1 + (size_t)(idx >> 2) * 384 + k0 + 32 + (idx & 3) * 8);
            }
        }
        shortx8 af[2];
        af[0] = *(shortx8*)(Cbuf + (l15) * CST + k0 + quad * 8);
        af[1] = *(shortx8*)(Cbuf + (16 + l15) * CST + k0 + quad * 8);
        #pragma unroll
        for (int j = 0; j < 6; ++j) {
            shortx8 bfr = *(shortx8*)(Wbuf + (wcol + j * 16 + l15) * WST + quad * 8);
            acc[0][j] = __builtin_amdgcn_mfma_f32_16x16x32_bf16(af[0], bfr, acc[0][j], 0, 0, 0);
            acc[1][j] = __builtin_amdgcn_mfma_f32_16x16x32_bf16(af[1], bfr, acc[1][j], 0, 0, 0);
        }
    }
    __syncthreads();
    #pragma unroll
    for (int j = 0; j < 6; ++j) {
        int col = wcol + j * 16 + l15;
        float bv = b1c[col];
        #pragma unroll
        for (int i = 0; i < 2; ++i)
            #pragma unroll
            for (int rr = 0; rr < 4; ++rr) {
                int row = i * 16 + quad * 4 + rr;
                Cbuf[row * CST + col] = f2bf(fmaxf(acc[i][j][rr] + bv, 0.f));
            }
    }
    __syncthreads();

    // ---------------- stage 3: x2 = hidden @ W2^T + b2 + h1 ----------------
    #pragma unroll
    for (int i = 0; i < 2; ++i)
        #pragma unroll
        for (int j = 0; j < 6; ++j) acc[i][j] = (floatx4){0.f, 0.f, 0.f, 0.f};
    #pragma unroll
    for (int cix = 0; cix < 6; ++cix) {
        int idx = cix * 256 + tid;
        wreg[cix] = *(const shortx8*)(W2 + (size_t)(idx >> 2) * 384 + (idx & 3) * 8);
    }
    for (int k0 = 0; k0 < 384; k0 += 32) {
        __syncthreads();
        #pragma unroll
        for (int cix = 0; cix < 6; ++cix) {
            int idx = cix * 256 + tid;
            *(shortx8*)(Wbuf + (idx >> 2) * WST + (idx & 3) * 8) = wreg[cix];
        }
        __syncthreads();
        if (k0 + 32 < 384) {
            #pragma unroll
            for (int cix = 0; cix < 6; ++cix) {
                int idx = cix * 256 + tid;
                wreg[cix] = *(const shortx8*)(W2 + (size_t)(idx >> 2) * 384 + k0 + 32 + (idx & 3) * 8);
            }
        }
        shortx8 af[2];
        af[0] = *(shortx8*)(Cbuf + (l15) * CST + k0 + quad * 8);
        af[1] = *(shortx8*)(Cbuf + (16 + l15) * CST + k0 + quad * 8);
        #pragma unroll
        for (int j = 0; j < 6; ++j) {
            shortx8 bfr = *(shortx8*)(Wbuf + (wcol + j * 16 + l15) * WST + quad * 8);
            acc[0][j] = __builtin_amdgcn_mfma_f32_16x16x32_bf16(af[0], bfr, acc[0][j], 0, 0, 0);
            acc[1][j] = __builtin_amdgcn_mfma_f32_16x16x32_bf16(af[1], bfr, acc[1][j], 0, 0, 0);
        }
    }
    __syncthreads();
    #pragma unroll
    for (int j = 0; j < 6; ++j) {
        int col = wcol + j * 16 + l15;
        float bv = b2c[col];
        #pragma unroll
        for (int i = 0; i < 2; ++i)
            #pragma unroll
            for (int rr = 0; rr < 4; ++rr) {
                int row = i * 16 + quad * 4 + rr;
                int gr = min(by0 + row, LEN - 1);
                float x = acc[i][j][rr] + bv + h1f[(size_t)gr * 384 + col];
                Cbuf[row * CST + col] = f2bf(x);
            }
    }
    __syncthreads();

    // ---- LN2 -> d_out ----
    {
        int row = tid >> 3, part = tid & 7;
        float sx = 0.f, qx = 0.f, sz = 0.f, qz = 0.f;
        #pragma unroll
        for (int m = 0; m < 6; ++m) {
            int c0 = part * 48 + m * 8;
            shortx8 v = *(shortx8*)(Cbuf + row * CST + c0);
            float cs = 0.f, cq = 0.f;
            #pragma unroll
            for (int e = 0; e < 8; ++e) { float x = bf2f(v[e]); cs += x; cq += x * x; }
            if (c0 < 256) { sx += cs; qx += cq; } else { sz += cs; qz += cq; }
        }
        pst4[row * 8 + part] = (floatx4){sx, qx, sz, qz};
    }
    __syncthreads();
    if (tid < MT) {
        floatx4 s = (floatx4){0.f, 0.f, 0.f, 0.f};
        #pragma unroll
        for (int p = 0; p < 8; ++p) s += pst4[tid * 8 + p];
        float mx = s[0] / 256.f, vx = s[1] / 256.f - mx * mx;
        float mz = s[2] / 128.f, vz = s[3] / 128.f - mz * mz;
        lnf[tid] = (floatx4){mx, rsqrtf(vx + 1e-5f), mz, rsqrtf(vz + 1e-5f)};
    }
    __syncthreads();
    {
        int row = tid >> 3, part = tid & 7;
        int gr = by0 + row;
        if (gr < LEN) {
            floatx4 L = lnf[row];
            #pragma unroll
            for (int m = 0; m < 6; ++m) {
                int c0 = part * 48 + m * 8;
                bool isxy = c0 < 256;
                float mean = isxy ? L[0] : L[2];
                float inv  = isxy ? L[1] : L[3];
                shortx8 v = *(shortx8*)(Cbuf + row * CST + c0);
                float4 g0 = *(const float4*)(l2g + c0), g1 = *(const float4*)(l2g + c0 + 4);
                float4 e0 = *(const float4*)(l2b + c0), e1 = *(const float4*)(l2b + c0 + 4);
                float gg[8] = {g0.x, g0.y, g0.z, g0.w, g1.x, g1.y, g1.z, g1.w};
                float ee[8] = {e0.x, e0.y, e0.z, e0.w, e1.x, e1.y, e1.z, e1.w};
                float h[8];
                #pragma unroll
                for (int e = 0; e < 8; ++e)
                    h[e] = (bf2f(v[e]) - mean) * inv * gg[e] + ee[e];
                *(float4*)(outp + (size_t)gr * 384 + c0)     = make_float4(h[0], h[1], h[2], h[3]);
                *(float4*)(outp + (size_t)gr * 384 + c0 + 4) = make_float4(h[4], h[5], h[6], h[7]);
            }
        }
    }
}

// ---------------------------------------------------------------------------
extern "C" void kernel_launch(void* const* d_in, const int* in_sizes, int n_in,
                              void* d_out, int out_size, void* d_ws, size_t ws_size,
                              hipStream_t stream) {
    const float* src    = (const float*)d_in[0];
    const float* pos    = (const float*)d_in[3];
    const float* refpts = (const float*)d_in[4];
    const float* W_off  = (const float*)d_in[8];
    const float* b_off  = (const float*)d_in[9];
    const float* W_attn = (const float*)d_in[10];
    const float* b_attn = (const float*)d_in[11];
    const float* W_val  = (const float*)d_in[12];
    const float* b_val  = (const float*)d_in[13];
    const float* W_out  = (const float*)d_in[14];
    const float* b_out  = (const float*)d_in[15];
    const float* g1xy = (const float*)d_in[16]; const float* b1xy = (const float*)d_in[17];
    const float* g1zd = (const float*)d_in[18]; const float* b1zd = (const float*)d_in[19];
    const float* fxy_w1 = (const float*)d_in[20]; const float* fxy_b1 = (const float*)d_in[21];
    const float* fxy_w2 = (const float*)d_in[22]; const float* fxy_b2 = (const float*)d_in[23];
    const float* fxy_g  = (const float*)d_in[24]; const float* fxy_b  = (const float*)d_in[25];
    const float* fzd_w1 = (const float*)d_in[26]; const float* fzd_b1 = (const float*)d_in[27];
    const float* fzd_w2 = (const float*)d_in[28]; const float* fzd_b2 = (const float*)d_in[29];
    const float* fzd_g  = (const float*)d_in[30]; const float* fzd_b  = (const float*)d_in[31];

    float* out = (float*)d_out;
    size_t Rn = (size_t)LEN * DMODEL;

    float* f0 = (float*)d_ws;                 // offattn fp32, later h1 fp32
    ushort* sb = (ushort*)(f0 + Rn);
    ushort* s0 = sb;                          // src_bf
    ushort* s1 = sb + Rn;                     // q_bf
    ushort* s2 = sb + 2 * Rn;                 // value_bf
    ushort* s3 = sb + 3 * Rn;                 // msda_bf
    ushort* wv  = sb + 4 * Rn;
    ushort* woa = wv + WSZ;
    ushort* wo  = woa + WSZ;
    ushort* w1b = wo + WSZ;
    ushort* w2b = w1b + WSZ;
    float* bp = (float*)(w2b + WSZ);
    float* boa = bp;        float* b1c = bp + 384;  float* b2c = bp + 768;
    float* l1g = bp + 1152; float* l1b = bp + 1536;
    float* l2g = bp + 1920; float* l2b = bp + 2304;

    prep_w<<<dim3((WSZ + 255) / 256, 5), 256, 0, stream>>>(
        W_val, W_off, W_attn, W_out, fxy_w1, fzd_w1, fxy_w2, fzd_w2,
        wv, woa, wo, w1b, w2b);
    prep_b<<<1, 384, 0, stream>>>(b_off, b_attn, fxy_b1, fzd_b1, fxy_b2, fzd_b2,
                                  g1xy, b1xy, g1zd, b1zd, fxy_g, fxy_b, fzd_g, fzd_b,
                                  boa, b1c, b2c, l1g, l1b, l2g, l2b);

    int n8 = (int)(Rn / 8);
    cvt_add<<<(n8 + 255) / 256, 256, 0, stream>>>(src, pos, s0, s1, n8);

    vq_gemm<<<dim3(6, (LEN + TSV - 1) / TSV), 256, 0, stream>>>(
        s0, s1, wv, woa, b_val, boa, s2, f0);

    msda_v3<<<(LEN + MTOK - 1) / MTOK, 384, 0, stream>>>(s2, f0, refpts, s3);

    mega_kernel<<<(LEN + MT - 1) / MT, 256, 0, stream>>>(
        s3, src, wo, w1b, w2b, b_out, b1c, b2c,
        l1g, l1b, l2g, l2b, f0, out);
}